// Round 7
// baseline (287.086 us; speedup 1.0000x reference)
//
#include <hip/hip_runtime.h>
#include <hip/hip_cooperative_groups.h>

namespace cg = cooperative_groups;

#define EMB 64
#define BKT_BITS 9                 // 512 rows per bucket
#define BKT_ROWS (1 << BKT_BITS)
#define BKT_CAP 4608               // fixed bucket capacity (mean 4096, +8 sigma)
#define MAX_BKT 512                // supports up to 262144 nodes
#define CO_EDGES 2048              // edges per coarse chunk (~586 chunks)
#define NSHARD 8                   // column shards for convoy ordering

typedef float f32x4 __attribute__((ext_vector_type(4)));

// ---------------- shared device bodies (used by mega + fallback) ----------

__device__ __forceinline__ const float4* xrow(const float* xu,
                                              const float* xi,
                                              int nu, int col) {
    return (const float4*)((col < nu) ? (xu + (size_t)col * EMB)
                                      : (xi + (size_t)(col - nu) * EMB));
}

// Coarse scatter: bin a chunk by bucket in LDS, reserve per-bucket ranges
// with one global atomic per (chunk,bucket), scatter into fixed regions of
// es_raw. Packs row's low 9 bits above the 18-bit col.
__device__ void coarse_body(const int* __restrict__ rows,
                            const int* __restrict__ cols,
                            const float* __restrict__ vals,
                            int* bcur, int2* __restrict__ es_raw,
                            int n_edges, int nbkt,
                            int* lcnt, int* lbase,
                            int cstart, int cstride) {
    int tid = threadIdx.x;           // blockDim.x == 512
    int nchunk = (n_edges + CO_EDGES - 1) / CO_EDGES;
    for (int c = cstart; c < nchunk; c += cstride) {
        for (int i = tid; i < nbkt; i += 512) lcnt[i] = 0;
        __syncthreads();
        int e0 = c * CO_EDGES;
        int e1 = min(e0 + CO_EDGES, n_edges);
        for (int e = e0 + tid; e < e1; e += 512)
            atomicAdd(&lcnt[rows[e] >> BKT_BITS], 1);
        __syncthreads();
        for (int i = tid; i < nbkt; i += 512) {
            int cc = lcnt[i];
            lbase[i] = cc ? atomicAdd(&bcur[i], cc) : 0;
        }
        __syncthreads();
        for (int e = e0 + tid; e < e1; e += 512) {
            int r = rows[e];
            int b = r >> BKT_BITS;
            int p = atomicAdd(&lbase[b], 1);
            if (p < BKT_CAP)   // statistically unreachable; guards corruption
                es_raw[(size_t)b * BKT_CAP + p] =
                    make_int2(cols[e] | ((r & (BKT_ROWS - 1)) << 18),
                              __float_as_int(vals[e]));
        }
        __syncthreads();
    }
}

// Fine permute with CONVOY ordering: group by key = (rowlocal, col-shard)
// via a 4096-counter LDS histogram + in-LDS scan. Each row's edges come
// out sorted by column shard, so concurrently-processed rows walk the x
// array in the same order -> device-wide gather footprint shrinks from
// 38.4 MB to a moving ~6 MB window -> L2 hit rate up. Also emits per-row
// [beg,end) (rbe), coalesced. LDS: 18 KB, no staging (round-5 lesson).
__device__ void fine_body(const int* bcur,
                          const int2* __restrict__ es_raw,
                          int2* __restrict__ es,
                          int2* __restrict__ rbe, int n_nodes, int nbkt,
                          int sdiv,
                          int* kcnt, int* s512,
                          int bstart, int bstride) {
    int tid = threadIdx.x;          // blockDim.x == 512 == BKT_ROWS
    for (int b = bstart; b < nbkt; b += bstride) {
        int cnt = min(bcur[b], BKT_CAP);
        int base = b * BKT_CAP;
        int kb = tid * NSHARD;      // thread tid owns row tid's 8 shard keys
        #pragma unroll
        for (int k = 0; k < NSHARD; ++k) kcnt[kb + k] = 0;
        __syncthreads();
        for (int j = tid; j < cnt; j += BKT_ROWS) {
            int2 e = es_raw[base + j];
            int key = ((e.x >> 18) << 3) | ((e.x & 0x3FFFF) / sdiv);
            atomicAdd(&kcnt[key], 1);
        }
        __syncthreads();
        // serial exclusive scan over this thread's 8 keys; run = row total
        int run = 0;
        #pragma unroll
        for (int k = 0; k < NSHARD; ++k) {
            int c = kcnt[kb + k];
            kcnt[kb + k] = run;
            run += c;
        }
        s512[tid] = run;
        __syncthreads();
        for (int d = 1; d < BKT_ROWS; d <<= 1) {
            int t = (tid >= d) ? s512[tid - d] : 0;
            __syncthreads();
            s512[tid] += t;
            __syncthreads();
        }
        int excl = s512[tid] - run;   // bucket-local row start
        #pragma unroll
        for (int k = 0; k < NSHARD; ++k) kcnt[kb + k] += excl;  // fill cursors
        int r = (b << BKT_BITS) + tid;
        if (r < n_nodes) rbe[r] = make_int2(base + excl, base + excl + run);
        __syncthreads();
        for (int j = tid; j < cnt; j += BKT_ROWS) {
            int2 e = es_raw[base + j];
            int col = e.x & 0x3FFFF;
            int key = ((e.x >> 18) << 3) | (col / sdiv);
            int p = atomicAdd(&kcnt[key], 1);
            es[base + p] = make_int2(col, e.y);
        }
        __syncthreads();
    }
}

// Row-parallel SpMM, 16 lanes/row, 4-wide edge unroll, grid-stride.
// mode 0/1: y = a, PLAIN store (y is next layer's gather source; NT here
//           cost +37 MB FETCH in round 4).
// mode 2:   out = 0.25*(x0[o] + y1[o] + y2[o] + a), NT store (never re-read).
__device__ void spmm_body(const int2* __restrict__ rbe,
                          const int2* __restrict__ es,
                          const float* xu, const float* xi, int nu,
                          float4* y, const float4* y1, const float4* y2,
                          const float* __restrict__ x0u,
                          const float* __restrict__ x0i,
                          int n_nodes, int mode, int gid0, int gstride) {
    int lanes = n_nodes * 16;
    for (int gid = gid0; gid < lanes; gid += gstride) {
        int r = gid >> 4;
        int q = gid & 15;
        int2 be = rbe[r];
        int beg = be.x;
        int end = be.y;
        float4 a = make_float4(0.f, 0.f, 0.f, 0.f);
        int j = beg;
        for (; j + 4 <= end; j += 4) {
            int2 e0 = es[j];
            int2 e1 = es[j + 1];
            int2 e2 = es[j + 2];
            int2 e3 = es[j + 3];
            float4 x0 = xrow(xu, xi, nu, e0.x)[q];
            float4 x1 = xrow(xu, xi, nu, e1.x)[q];
            float4 x2 = xrow(xu, xi, nu, e2.x)[q];
            float4 x3 = xrow(xu, xi, nu, e3.x)[q];
            float v0 = __int_as_float(e0.y);
            float v1 = __int_as_float(e1.y);
            float v2 = __int_as_float(e2.y);
            float v3 = __int_as_float(e3.y);
            a.x += v0 * x0.x; a.y += v0 * x0.y; a.z += v0 * x0.z; a.w += v0 * x0.w;
            a.x += v1 * x1.x; a.y += v1 * x1.y; a.z += v1 * x1.z; a.w += v1 * x1.w;
            a.x += v2 * x2.x; a.y += v2 * x2.y; a.z += v2 * x2.z; a.w += v2 * x2.w;
            a.x += v3 * x3.x; a.y += v3 * x3.y; a.z += v3 * x3.z; a.w += v3 * x3.w;
        }
        if (j + 2 <= end) {
            int2 e0 = es[j];
            int2 e1 = es[j + 1];
            float4 x0 = xrow(xu, xi, nu, e0.x)[q];
            float4 x1 = xrow(xu, xi, nu, e1.x)[q];
            float v0 = __int_as_float(e0.y);
            float v1 = __int_as_float(e1.y);
            a.x += v0 * x0.x; a.y += v0 * x0.y; a.z += v0 * x0.z; a.w += v0 * x0.w;
            a.x += v1 * x1.x; a.y += v1 * x1.y; a.z += v1 * x1.z; a.w += v1 * x1.w;
            j += 2;
        }
        if (j < end) {
            int2 e0 = es[j];
            float4 x0 = xrow(xu, xi, nu, e0.x)[q];
            float v0 = __int_as_float(e0.y);
            a.x += v0 * x0.x; a.y += v0 * x0.y; a.z += v0 * x0.z; a.w += v0 * x0.w;
        }
        size_t o = (size_t)r * (EMB / 4) + q;
        if (mode < 2) {
            y[o] = a;
        } else {
            const float4* b0 = (r < nu)
                ? ((const float4*)x0u + (size_t)r * (EMB / 4))
                : ((const float4*)x0i + (size_t)(r - nu) * (EMB / 4));
            float4 f0 = b0[q];
            float4 a1 = y1[o];
            float4 a2 = y2[o];
            float4 ac;
            ac.x = 0.25f * (f0.x + a1.x + a2.x + a.x);
            ac.y = 0.25f * (f0.y + a1.y + a2.y + a.y);
            ac.z = 0.25f * (f0.z + a1.z + a2.z + a.z);
            ac.w = 0.25f * (f0.w + a1.w + a2.w + a.w);
            __builtin_nontemporal_store(*(const f32x4*)&ac, (f32x4*)&y[o]);
        }
    }
}

// ---------------- single cooperative mega-kernel --------------------------
// LDS 18 KB (kcnt 16K + s512 2K); coarse aliases kcnt[0:1024) as lcnt/lbase.
// No min-waves in launch_bounds (round-5 lesson: (512,6) forced spills).
__global__ __launch_bounds__(512) void mega(
        const int* __restrict__ rows, const int* __restrict__ cols,
        const float* __restrict__ vals,
        int* bcur, int2* __restrict__ es_raw, int2* __restrict__ es,
        int2* __restrict__ rbe,
        const float* __restrict__ ue, const float* __restrict__ ie,
        float* y2buf, float* out,
        int nu, int n_nodes, int n_edges, int nbkt, int sdiv) {
    cg::grid_group grid = cg::this_grid();
    __shared__ int kcnt[BKT_ROWS * NSHARD];   // 16 KB
    __shared__ int s512[BKT_ROWS];            //  2 KB
    int gid0 = blockIdx.x * blockDim.x + threadIdx.x;
    int gstride = gridDim.x * blockDim.x;

    // P0: zero bucket cursors
    for (int i = gid0; i < nbkt; i += gstride) bcur[i] = 0;
    grid.sync();

    // P1: coarse scatter -> es_raw
    coarse_body(rows, cols, vals, bcur, es_raw, n_edges, nbkt,
                kcnt, kcnt + MAX_BKT, blockIdx.x, gridDim.x);
    grid.sync();

    // P2: fine permute es_raw -> es (convoy-ordered), emit rbe
    fine_body(bcur, es_raw, es, rbe, n_nodes, nbkt, sdiv, kcnt, s512,
              blockIdx.x, gridDim.x);
    grid.sync();

    // P3: layer 1, x = [ue;ie] -> y1 = out
    spmm_body(rbe, es, ue, ie, nu, (float4*)out,
              nullptr, nullptr, nullptr, nullptr, n_nodes, 0, gid0, gstride);
    grid.sync();

    // P4: layer 2, x = y1 -> y2buf
    spmm_body(rbe, es, out, out + (size_t)nu * EMB, nu, (float4*)y2buf,
              nullptr, nullptr, nullptr, nullptr, n_nodes, 1, gid0, gstride);
    grid.sync();

    // P5: layer 3, x = y2buf; out = 0.25*(x0 + y1 + y2 + a)
    spmm_body(rbe, es, y2buf, y2buf + (size_t)nu * EMB, nu, (float4*)out,
              (const float4*)out, (const float4*)y2buf, ue, ie,
              n_nodes, 2, gid0, gstride);
}

// ---------------- fallback multi-dispatch kernels -------------------------

__global__ __launch_bounds__(512) void k_coarse(
        const int* __restrict__ rows, const int* __restrict__ cols,
        const float* __restrict__ vals, int* bcur, int2* __restrict__ es_raw,
        int n_edges, int nbkt) {
    __shared__ int lcnt[MAX_BKT];
    __shared__ int lbase[MAX_BKT];
    coarse_body(rows, cols, vals, bcur, es_raw, n_edges, nbkt,
                lcnt, lbase, blockIdx.x, gridDim.x);
}

__global__ __launch_bounds__(512) void k_fine(
        const int* bcur, const int2* __restrict__ es_raw,
        int2* __restrict__ es, int2* __restrict__ rbe,
        int n_nodes, int nbkt, int sdiv) {
    __shared__ int kcnt[BKT_ROWS * NSHARD];
    __shared__ int s512[BKT_ROWS];
    fine_body(bcur, es_raw, es, rbe, n_nodes, nbkt, sdiv, kcnt, s512,
              blockIdx.x, gridDim.x);
}

__global__ __launch_bounds__(256) void k_spmm(
        const int2* __restrict__ rbe, const int2* __restrict__ es,
        const float* xu, const float* xi, int nu,
        float4* y, const float4* y1, const float4* y2,
        const float* __restrict__ x0u, const float* __restrict__ x0i,
        int n_nodes, int mode) {
    spmm_body(rbe, es, xu, xi, nu, y, y1, y2, x0u, x0i, n_nodes, mode,
              blockIdx.x * blockDim.x + threadIdx.x,
              gridDim.x * blockDim.x);
}

extern "C" void kernel_launch(void* const* d_in, const int* in_sizes, int n_in,
                              void* d_out, int out_size, void* d_ws, size_t ws_size,
                              hipStream_t stream) {
    const float* ue   = (const float*)d_in[0];
    const float* ie   = (const float*)d_in[1];
    const int*   rows = (const int*)d_in[2];
    const int*   cols = (const int*)d_in[3];
    const float* vals = (const float*)d_in[4];
    float* out = (float*)d_out;

    const int num_users = in_sizes[0] / EMB;
    const int num_items = in_sizes[1] / EMB;
    const int n_nodes   = num_users + num_items;
    const int n_edges   = in_sizes[2];
    const int nbkt      = (n_nodes + BKT_ROWS - 1) >> BKT_BITS;   // 293
    const int sdiv      = (n_nodes + NSHARD - 1) / NSHARD;        // 18750

    // Workspace (~61.3 MB):
    //  y2buf (38.4) | es (10.8) | es_raw (10.8) | rbe (1.2) | bcur (1.2 KB)
    const size_t buf_elems = (size_t)n_nodes * EMB;
    float* y2buf  = (float*)d_ws;
    int2*  es     = (int2*)(y2buf + buf_elems);
    int2*  es_raw = es + (size_t)nbkt * BKT_CAP;
    int2*  rbe    = es_raw + (size_t)nbkt * BKT_CAP;
    int*   bcur   = (int*)(rbe + n_nodes);

    int occ = 0, cus = 0, dev = 0;
    hipGetDevice(&dev);
    hipOccupancyMaxActiveBlocksPerMultiprocessor(&occ, mega, 512, 0);
    hipDeviceGetAttribute(&cus, hipDeviceAttributeMultiprocessorCount, dev);
    if (cus < 1) cus = 256;
    if (occ > 4) occ = 4;

    bool done = false;
    if (occ >= 3) {
        int grid_blocks = occ * cus;
        int nu = num_users, nn = n_nodes, ne = n_edges, nb = nbkt, sd = sdiv;
        void* args[] = { (void*)&rows, (void*)&cols, (void*)&vals,
                         (void*)&bcur, (void*)&es_raw, (void*)&es,
                         (void*)&rbe, (void*)&ue, (void*)&ie,
                         (void*)&y2buf, (void*)&out,
                         (void*)&nu, (void*)&nn, (void*)&ne, (void*)&nb,
                         (void*)&sd };
        hipError_t err = hipLaunchCooperativeKernel(
            mega, dim3(grid_blocks), dim3(512), args, 0, stream);
        done = (err == hipSuccess);
        if (!done) (void)hipGetLastError();
    }

    if (!done) {
        // Fallback: identical device code, classic dispatches.
        hipMemsetAsync(bcur, 0, (size_t)nbkt * sizeof(int), stream);
        int nchunk = (n_edges + CO_EDGES - 1) / CO_EDGES;
        k_coarse<<<nchunk, 512, 0, stream>>>(rows, cols, vals, bcur, es_raw,
                                             n_edges, nbkt);
        k_fine<<<nbkt, 512, 0, stream>>>(bcur, es_raw, es, rbe,
                                         n_nodes, nbkt, sdiv);
        int blocks = (n_nodes * 16 + 255) / 256;
        k_spmm<<<blocks, 256, 0, stream>>>(
            rbe, es, ue, ie, num_users, (float4*)out,
            nullptr, nullptr, nullptr, nullptr, n_nodes, 0);
        k_spmm<<<blocks, 256, 0, stream>>>(
            rbe, es, (const float*)out,
            (const float*)out + (size_t)num_users * EMB, num_users,
            (float4*)y2buf, nullptr, nullptr, nullptr, nullptr, n_nodes, 1);
        k_spmm<<<blocks, 256, 0, stream>>>(
            rbe, es, y2buf, y2buf + (size_t)num_users * EMB, num_users,
            (float4*)out, (const float4*)out, (const float4*)y2buf,
            ue, ie, n_nodes, 2);
    }
}

// Round 8
// 284.822 us; speedup vs baseline: 1.0079x; 1.0079x over previous
//
#include <hip/hip_runtime.h>
#include <hip/hip_cooperative_groups.h>

namespace cg = cooperative_groups;

#define EMB 64
#define BKT_BITS 9                 // 512 rows per bucket
#define BKT_ROWS (1 << BKT_BITS)
#define BKT_CAP 4608               // fixed bucket capacity (mean 4096, +8 sigma)
#define MAX_BKT 512                // supports up to 262144 nodes
#define CO_EDGES 2048              // edges per coarse chunk (~586 chunks)

typedef float f32x4 __attribute__((ext_vector_type(4)));
// 16-B edge-pair load type with 8-B alignment promise (es entries are 8-B
// aligned; backend emits dwordx4 when legal, else splits -- both correct).
typedef int int4e __attribute__((ext_vector_type(4), aligned(8)));

// ---------------- shared device bodies (used by mega + fallback) ----------

__device__ __forceinline__ const float4* xrow(const float* xu,
                                              const float* xi,
                                              int nu, int col) {
    return (const float4*)((col < nu) ? (xu + (size_t)col * EMB)
                                      : (xi + (size_t)(col - nu) * EMB));
}

// Coarse scatter: bin a chunk by bucket in LDS, reserve per-bucket ranges
// with one global atomic per (chunk,bucket), scatter into fixed regions of
// es_raw. Packs row's low 9 bits above the 18-bit col.
__device__ void coarse_body(const int* __restrict__ rows,
                            const int* __restrict__ cols,
                            const float* __restrict__ vals,
                            int* bcur, int2* __restrict__ es_raw,
                            int n_edges, int nbkt,
                            int* lcnt, int* lbase,
                            int cstart, int cstride) {
    int tid = threadIdx.x;           // blockDim.x == 512
    int nchunk = (n_edges + CO_EDGES - 1) / CO_EDGES;
    for (int c = cstart; c < nchunk; c += cstride) {
        for (int i = tid; i < nbkt; i += 512) lcnt[i] = 0;
        __syncthreads();
        int e0 = c * CO_EDGES;
        int e1 = min(e0 + CO_EDGES, n_edges);
        for (int e = e0 + tid; e < e1; e += 512)
            atomicAdd(&lcnt[rows[e] >> BKT_BITS], 1);
        __syncthreads();
        for (int i = tid; i < nbkt; i += 512) {
            int cc = lcnt[i];
            lbase[i] = cc ? atomicAdd(&bcur[i], cc) : 0;
        }
        __syncthreads();
        for (int e = e0 + tid; e < e1; e += 512) {
            int r = rows[e];
            int b = r >> BKT_BITS;
            int p = atomicAdd(&lbase[b], 1);
            if (p < BKT_CAP)   // statistically unreachable; guards corruption
                es_raw[(size_t)b * BKT_CAP + p] =
                    make_int2(cols[e] | ((r & (BKT_ROWS - 1)) << 18),
                              __float_as_int(vals[e]));
        }
        __syncthreads();
    }
}

// Fine permute, plain row grouping (convoy ordering removed: round-7
// falsified it -- FETCH unchanged, +150K LDS conflicts). Two passes over
// es_raw (L2-resident): count per-row -> LDS scan (emits per-row [beg,end)
// coalesced) -> permute into row-grouped es (row bits stripped). LDS 4 KB.
__device__ void fine_body(const int* bcur,
                          const int2* __restrict__ es_raw,
                          int2* __restrict__ es,
                          int2* __restrict__ rbe, int n_nodes, int nbkt,
                          int* rcnt, int* rsc,
                          int bstart, int bstride) {
    int tid = threadIdx.x;          // blockDim.x == 512 == BKT_ROWS
    for (int b = bstart; b < nbkt; b += bstride) {
        int cnt = min(bcur[b], BKT_CAP);
        int base = b * BKT_CAP;
        rcnt[tid] = 0;
        __syncthreads();
        for (int j = tid; j < cnt; j += BKT_ROWS)
            atomicAdd(&rcnt[es_raw[base + j].x >> 18], 1);
        __syncthreads();
        int v = rcnt[tid];
        rsc[tid] = v;
        __syncthreads();
        for (int d = 1; d < BKT_ROWS; d <<= 1) {
            int t = (tid >= d) ? rsc[tid - d] : 0;
            __syncthreads();
            rsc[tid] += t;
            __syncthreads();
        }
        int excl = rsc[tid] - v;
        rcnt[tid] = excl;           // fill cursor
        int r = (b << BKT_BITS) + tid;
        if (r < n_nodes) rbe[r] = make_int2(base + excl, base + excl + v);
        __syncthreads();
        for (int j = tid; j < cnt; j += BKT_ROWS) {
            int2 e = es_raw[base + j];
            int p = atomicAdd(&rcnt[e.x >> 18], 1);
            es[base + p] = make_int2(e.x & 0x3FFFF, e.y);
        }
        __syncthreads();
    }
}

// Row-parallel SpMM, 16 lanes/row, 4-wide edge unroll with 16-B es loads
// (2 edges per load: fewer live regs on the es side so the allocator can
// keep all 4 x-gathers in flight -- mega compiled to VGPR=24 in rounds 6/7,
// below the 4-deep pipeline's needs).
// mode 0/1: y = a, PLAIN store (y is next layer's gather source; NT here
//           cost +37 MB FETCH in round 4).
// mode 2:   out = 0.25*(x0[o] + y1[o] + y2[o] + a), NT store (never re-read).
__device__ void spmm_body(const int2* __restrict__ rbe,
                          const int2* __restrict__ es,
                          const float* xu, const float* xi, int nu,
                          float4* y, const float4* y1, const float4* y2,
                          const float* __restrict__ x0u,
                          const float* __restrict__ x0i,
                          int n_nodes, int mode, int gid0, int gstride) {
    int lanes = n_nodes * 16;
    for (int gid = gid0; gid < lanes; gid += gstride) {
        int r = gid >> 4;
        int q = gid & 15;
        int2 be = rbe[r];
        int beg = be.x;
        int end = be.y;
        float4 a = make_float4(0.f, 0.f, 0.f, 0.f);
        int j = beg;
        for (; j + 4 <= end; j += 4) {
            int4e p01 = *(const int4e*)(es + j);       // edges j, j+1
            int4e p23 = *(const int4e*)(es + j + 2);   // edges j+2, j+3
            const float4* r0 = xrow(xu, xi, nu, p01.x);
            const float4* r1 = xrow(xu, xi, nu, p01.z);
            const float4* r2 = xrow(xu, xi, nu, p23.x);
            const float4* r3 = xrow(xu, xi, nu, p23.z);
            float4 x0 = r0[q];
            float4 x1 = r1[q];
            float4 x2 = r2[q];
            float4 x3 = r3[q];
            float v0 = __int_as_float(p01.y);
            float v1 = __int_as_float(p01.w);
            float v2 = __int_as_float(p23.y);
            float v3 = __int_as_float(p23.w);
            a.x += v0 * x0.x; a.y += v0 * x0.y; a.z += v0 * x0.z; a.w += v0 * x0.w;
            a.x += v1 * x1.x; a.y += v1 * x1.y; a.z += v1 * x1.z; a.w += v1 * x1.w;
            a.x += v2 * x2.x; a.y += v2 * x2.y; a.z += v2 * x2.z; a.w += v2 * x2.w;
            a.x += v3 * x3.x; a.y += v3 * x3.y; a.z += v3 * x3.z; a.w += v3 * x3.w;
        }
        if (j + 2 <= end) {
            int4e p01 = *(const int4e*)(es + j);
            const float4* r0 = xrow(xu, xi, nu, p01.x);
            const float4* r1 = xrow(xu, xi, nu, p01.z);
            float4 x0 = r0[q];
            float4 x1 = r1[q];
            float v0 = __int_as_float(p01.y);
            float v1 = __int_as_float(p01.w);
            a.x += v0 * x0.x; a.y += v0 * x0.y; a.z += v0 * x0.z; a.w += v0 * x0.w;
            a.x += v1 * x1.x; a.y += v1 * x1.y; a.z += v1 * x1.z; a.w += v1 * x1.w;
            j += 2;
        }
        if (j < end) {
            int2 e0 = es[j];
            float4 x0 = xrow(xu, xi, nu, e0.x)[q];
            float v0 = __int_as_float(e0.y);
            a.x += v0 * x0.x; a.y += v0 * x0.y; a.z += v0 * x0.z; a.w += v0 * x0.w;
        }
        size_t o = (size_t)r * (EMB / 4) + q;
        if (mode < 2) {
            y[o] = a;
        } else {
            const float4* b0 = (r < nu)
                ? ((const float4*)x0u + (size_t)r * (EMB / 4))
                : ((const float4*)x0i + (size_t)(r - nu) * (EMB / 4));
            float4 f0 = b0[q];
            float4 a1 = y1[o];
            float4 a2 = y2[o];
            float4 ac;
            ac.x = 0.25f * (f0.x + a1.x + a2.x + a.x);
            ac.y = 0.25f * (f0.y + a1.y + a2.y + a.y);
            ac.z = 0.25f * (f0.z + a1.z + a2.z + a.z);
            ac.w = 0.25f * (f0.w + a1.w + a2.w + a.w);
            __builtin_nontemporal_store(*(const f32x4*)&ac, (f32x4*)&y[o]);
        }
    }
}

// ---------------- single cooperative mega-kernel --------------------------
// 4 grid.syncs (P0 zeroing moved to a host-side hipMemsetAsync -- each sync
// costs a cross-XCD visibility drain, so fewer syncs = less serial drain).
// LDS 8 KB. No min-waves in launch_bounds (round-5: (512,6) forced spills).
__global__ __launch_bounds__(512) void mega(
        const int* __restrict__ rows, const int* __restrict__ cols,
        const float* __restrict__ vals,
        int* bcur, int2* __restrict__ es_raw, int2* __restrict__ es,
        int2* __restrict__ rbe,
        const float* __restrict__ ue, const float* __restrict__ ie,
        float* y2buf, float* out,
        int nu, int n_nodes, int n_edges, int nbkt) {
    cg::grid_group grid = cg::this_grid();
    __shared__ int lcnt[MAX_BKT];     // 2 KB (coarse)
    __shared__ int lbase[MAX_BKT];    // 2 KB (coarse)
    __shared__ int rcnt[BKT_ROWS];    // 2 KB (fine)
    __shared__ int rsc[BKT_ROWS];     // 2 KB (fine)
    int gid0 = blockIdx.x * blockDim.x + threadIdx.x;
    int gstride = gridDim.x * blockDim.x;

    // P1: coarse scatter -> es_raw (bcur pre-zeroed by host memset)
    coarse_body(rows, cols, vals, bcur, es_raw, n_edges, nbkt,
                lcnt, lbase, blockIdx.x, gridDim.x);
    grid.sync();

    // P2: fine permute es_raw -> es, emit rbe
    fine_body(bcur, es_raw, es, rbe, n_nodes, nbkt, rcnt, rsc,
              blockIdx.x, gridDim.x);
    grid.sync();

    // P3: layer 1, x = [ue;ie] -> y1 = out
    spmm_body(rbe, es, ue, ie, nu, (float4*)out,
              nullptr, nullptr, nullptr, nullptr, n_nodes, 0, gid0, gstride);
    grid.sync();

    // P4: layer 2, x = y1 -> y2buf
    spmm_body(rbe, es, out, out + (size_t)nu * EMB, nu, (float4*)y2buf,
              nullptr, nullptr, nullptr, nullptr, n_nodes, 1, gid0, gstride);
    grid.sync();

    // P5: layer 3, x = y2buf; out = 0.25*(x0 + y1 + y2 + a)
    spmm_body(rbe, es, y2buf, y2buf + (size_t)nu * EMB, nu, (float4*)out,
              (const float4*)out, (const float4*)y2buf, ue, ie,
              n_nodes, 2, gid0, gstride);
}

// ---------------- fallback multi-dispatch kernels -------------------------

__global__ __launch_bounds__(512) void k_coarse(
        const int* __restrict__ rows, const int* __restrict__ cols,
        const float* __restrict__ vals, int* bcur, int2* __restrict__ es_raw,
        int n_edges, int nbkt) {
    __shared__ int lcnt[MAX_BKT];
    __shared__ int lbase[MAX_BKT];
    coarse_body(rows, cols, vals, bcur, es_raw, n_edges, nbkt,
                lcnt, lbase, blockIdx.x, gridDim.x);
}

__global__ __launch_bounds__(512) void k_fine(
        const int* bcur, const int2* __restrict__ es_raw,
        int2* __restrict__ es, int2* __restrict__ rbe,
        int n_nodes, int nbkt) {
    __shared__ int rcnt[BKT_ROWS];
    __shared__ int rsc[BKT_ROWS];
    fine_body(bcur, es_raw, es, rbe, n_nodes, nbkt, rcnt, rsc,
              blockIdx.x, gridDim.x);
}

__global__ __launch_bounds__(256) void k_spmm(
        const int2* __restrict__ rbe, const int2* __restrict__ es,
        const float* xu, const float* xi, int nu,
        float4* y, const float4* y1, const float4* y2,
        const float* __restrict__ x0u, const float* __restrict__ x0i,
        int n_nodes, int mode) {
    spmm_body(rbe, es, xu, xi, nu, y, y1, y2, x0u, x0i, n_nodes, mode,
              blockIdx.x * blockDim.x + threadIdx.x,
              gridDim.x * blockDim.x);
}

extern "C" void kernel_launch(void* const* d_in, const int* in_sizes, int n_in,
                              void* d_out, int out_size, void* d_ws, size_t ws_size,
                              hipStream_t stream) {
    const float* ue   = (const float*)d_in[0];
    const float* ie   = (const float*)d_in[1];
    const int*   rows = (const int*)d_in[2];
    const int*   cols = (const int*)d_in[3];
    const float* vals = (const float*)d_in[4];
    float* out = (float*)d_out;

    const int num_users = in_sizes[0] / EMB;
    const int num_items = in_sizes[1] / EMB;
    const int n_nodes   = num_users + num_items;
    const int n_edges   = in_sizes[2];
    const int nbkt      = (n_nodes + BKT_ROWS - 1) >> BKT_BITS;   // 293

    // Workspace (~61.3 MB):
    //  y2buf (38.4) | es (10.8) | es_raw (10.8) | rbe (1.2) | bcur (1.2 KB)
    const size_t buf_elems = (size_t)n_nodes * EMB;
    float* y2buf  = (float*)d_ws;
    int2*  es     = (int2*)(y2buf + buf_elems);
    int2*  es_raw = es + (size_t)nbkt * BKT_CAP;
    int2*  rbe    = es_raw + (size_t)nbkt * BKT_CAP;
    int*   bcur   = (int*)(rbe + n_nodes);

    int occ = 0, cus = 0, dev = 0;
    hipGetDevice(&dev);
    hipOccupancyMaxActiveBlocksPerMultiprocessor(&occ, mega, 512, 0);
    hipDeviceGetAttribute(&cus, hipDeviceAttributeMultiprocessorCount, dev);
    if (cus < 1) cus = 256;
    if (occ > 4) occ = 4;

    // zero bucket cursors (stream-ordered; replaces mega's old P0 + sync)
    hipMemsetAsync(bcur, 0, (size_t)nbkt * sizeof(int), stream);

    bool done = false;
    if (occ >= 3) {
        int grid_blocks = occ * cus;
        int nu = num_users, nn = n_nodes, ne = n_edges, nb = nbkt;
        void* args[] = { (void*)&rows, (void*)&cols, (void*)&vals,
                         (void*)&bcur, (void*)&es_raw, (void*)&es,
                         (void*)&rbe, (void*)&ue, (void*)&ie,
                         (void*)&y2buf, (void*)&out,
                         (void*)&nu, (void*)&nn, (void*)&ne, (void*)&nb };
        hipError_t err = hipLaunchCooperativeKernel(
            mega, dim3(grid_blocks), dim3(512), args, 0, stream);
        done = (err == hipSuccess);
        if (!done) (void)hipGetLastError();
    }

    if (!done) {
        // Fallback: identical device code, classic dispatches.
        int nchunk = (n_edges + CO_EDGES - 1) / CO_EDGES;
        k_coarse<<<nchunk, 512, 0, stream>>>(rows, cols, vals, bcur, es_raw,
                                             n_edges, nbkt);
        k_fine<<<nbkt, 512, 0, stream>>>(bcur, es_raw, es, rbe,
                                         n_nodes, nbkt);
        int blocks = (n_nodes * 16 + 255) / 256;
        k_spmm<<<blocks, 256, 0, stream>>>(
            rbe, es, ue, ie, num_users, (float4*)out,
            nullptr, nullptr, nullptr, nullptr, n_nodes, 0);
        k_spmm<<<blocks, 256, 0, stream>>>(
            rbe, es, (const float*)out,
            (const float*)out + (size_t)num_users * EMB, num_users,
            (float4*)y2buf, nullptr, nullptr, nullptr, nullptr, n_nodes, 1);
        k_spmm<<<blocks, 256, 0, stream>>>(
            rbe, es, y2buf, y2buf + (size_t)num_users * EMB, num_users,
            (float4*)out, (const float4*)out, (const float4*)y2buf,
            ue, ie, n_nodes, 2);
    }
}

// Round 9
// 240.002 us; speedup vs baseline: 1.1962x; 1.1867x over previous
//
#include <hip/hip_runtime.h>
#include <hip/hip_fp16.h>
#include <hip/hip_cooperative_groups.h>

namespace cg = cooperative_groups;

#define EMB 64
#define BKT_BITS 9                 // 512 rows per bucket
#define BKT_ROWS (1 << BKT_BITS)
#define BKT_CAP 4608               // fixed bucket capacity (mean 4096, +8 sigma)
#define MAX_BKT 512                // supports up to 262144 nodes
#define CO_EDGES 2048              // edges per coarse chunk (~586 chunks)

typedef float f32x4 __attribute__((ext_vector_type(4)));
typedef int int4e __attribute__((ext_vector_type(4), aligned(8)));
typedef unsigned short ushort_t;

// ---------------- shared device bodies (used by mega + fallback) ----------

// Convert fp32 [ue;ie] -> contiguous fp16 xh (the gathered operand).
// fp16 gather rows are 128 B (vs 256): halves gather bytes AND working set.
__device__ void convert_body(const float4* __restrict__ ue4,
                             const float4* __restrict__ ie4,
                             int nu16, uint2* __restrict__ xh2,
                             int lanes, int gid0, int gstride) {
    for (int o = gid0; o < lanes; o += gstride) {
        float4 v = (o < nu16) ? ue4[o] : ie4[o - nu16];
        __half2 lo = __floats2half2_rn(v.x, v.y);
        __half2 hi = __floats2half2_rn(v.z, v.w);
        xh2[o] = make_uint2(__builtin_bit_cast(unsigned, lo),
                            __builtin_bit_cast(unsigned, hi));
    }
}

// Coarse scatter: bin a chunk by bucket in LDS, reserve per-bucket ranges
// with one global atomic per (chunk,bucket), scatter into fixed regions of
// es_raw. Packs row's low 9 bits above the 18-bit col.
__device__ void coarse_body(const int* __restrict__ rows,
                            const int* __restrict__ cols,
                            const float* __restrict__ vals,
                            int* bcur, int2* __restrict__ es_raw,
                            int n_edges, int nbkt,
                            int* lcnt, int* lbase,
                            int cstart, int cstride) {
    int tid = threadIdx.x;           // blockDim.x == 512
    int nchunk = (n_edges + CO_EDGES - 1) / CO_EDGES;
    for (int c = cstart; c < nchunk; c += cstride) {
        for (int i = tid; i < nbkt; i += 512) lcnt[i] = 0;
        __syncthreads();
        int e0 = c * CO_EDGES;
        int e1 = min(e0 + CO_EDGES, n_edges);
        for (int e = e0 + tid; e < e1; e += 512)
            atomicAdd(&lcnt[rows[e] >> BKT_BITS], 1);
        __syncthreads();
        for (int i = tid; i < nbkt; i += 512) {
            int cc = lcnt[i];
            lbase[i] = cc ? atomicAdd(&bcur[i], cc) : 0;
        }
        __syncthreads();
        for (int e = e0 + tid; e < e1; e += 512) {
            int r = rows[e];
            int b = r >> BKT_BITS;
            int p = atomicAdd(&lbase[b], 1);
            if (p < BKT_CAP)   // statistically unreachable; guards corruption
                es_raw[(size_t)b * BKT_CAP + p] =
                    make_int2(cols[e] | ((r & (BKT_ROWS - 1)) << 18),
                              __float_as_int(vals[e]));
        }
        __syncthreads();
    }
}

// Fine permute (plain row grouping; convoy falsified in round 7). Two
// passes over es_raw (L2-resident): count -> LDS scan (emits per-row
// [beg,end) coalesced) -> permute into row-grouped es. LDS 4 KB.
__device__ void fine_body(const int* bcur,
                          const int2* __restrict__ es_raw,
                          int2* __restrict__ es,
                          int2* __restrict__ rbe, int n_nodes, int nbkt,
                          int* rcnt, int* rsc,
                          int bstart, int bstride) {
    int tid = threadIdx.x;          // blockDim.x == 512 == BKT_ROWS
    for (int b = bstart; b < nbkt; b += bstride) {
        int cnt = min(bcur[b], BKT_CAP);
        int base = b * BKT_CAP;
        rcnt[tid] = 0;
        __syncthreads();
        for (int j = tid; j < cnt; j += BKT_ROWS)
            atomicAdd(&rcnt[es_raw[base + j].x >> 18], 1);
        __syncthreads();
        int v = rcnt[tid];
        rsc[tid] = v;
        __syncthreads();
        for (int d = 1; d < BKT_ROWS; d <<= 1) {
            int t = (tid >= d) ? rsc[tid - d] : 0;
            __syncthreads();
            rsc[tid] += t;
            __syncthreads();
        }
        int excl = rsc[tid] - v;
        rcnt[tid] = excl;           // fill cursor
        int r = (b << BKT_BITS) + tid;
        if (r < n_nodes) rbe[r] = make_int2(base + excl, base + excl + v);
        __syncthreads();
        for (int j = tid; j < cnt; j += BKT_ROWS) {
            int2 e = es_raw[base + j];
            int p = atomicAdd(&rcnt[e.x >> 18], 1);
            es[base + p] = make_int2(e.x & 0x3FFFF, e.y);
        }
        __syncthreads();
    }
}

// fp16 row fragment (8 B = 4 halves) -> fp32 FMA into the accumulator.
__device__ __forceinline__ void fmad_h(float4& a, float v, uint2 g) {
    __half2 h0 = __builtin_bit_cast(__half2, g.x);
    __half2 h1 = __builtin_bit_cast(__half2, g.y);
    float2 f0 = __half22float2(h0);
    float2 f1 = __half22float2(h1);
    a.x += v * f0.x; a.y += v * f0.y; a.z += v * f1.x; a.w += v * f1.y;
}

// Row-parallel SpMM, 16 lanes/row, 4-wide edge unroll, fp16 gathers
// (lane q reads 8 B of the 128-B row), fp32 accumulation in registers.
// mode 0/1: yh[o] = fp16(a), plain store (next layer's gather source).
// mode 2:   out = 0.25*(x0_fp32[o] + y1h[o] + y2h[o] + a), NT fp32 store.
__device__ void spmm_body(const int2* __restrict__ rbe,
                          const int2* __restrict__ es,
                          const ushort_t* __restrict__ xh,
                          ushort_t* __restrict__ yh,
                          const ushort_t* __restrict__ y1h,
                          const ushort_t* __restrict__ y2h,
                          const float* __restrict__ x0u,
                          const float* __restrict__ x0i, int nu,
                          float4* __restrict__ out,
                          int n_nodes, int mode, int gid0, int gstride) {
    int lanes = n_nodes * 16;
    for (int gid = gid0; gid < lanes; gid += gstride) {
        int r = gid >> 4;
        int q = gid & 15;
        int2 be = rbe[r];
        int j = be.x;
        int end = be.y;
        float4 a = make_float4(0.f, 0.f, 0.f, 0.f);
        for (; j + 4 <= end; j += 4) {
            int4e p01 = *(const int4e*)(es + j);       // edges j, j+1
            int4e p23 = *(const int4e*)(es + j + 2);   // edges j+2, j+3
            uint2 g0 = *((const uint2*)(xh + (size_t)p01.x * EMB) + q);
            uint2 g1 = *((const uint2*)(xh + (size_t)p01.z * EMB) + q);
            uint2 g2 = *((const uint2*)(xh + (size_t)p23.x * EMB) + q);
            uint2 g3 = *((const uint2*)(xh + (size_t)p23.z * EMB) + q);
            fmad_h(a, __int_as_float(p01.y), g0);
            fmad_h(a, __int_as_float(p01.w), g1);
            fmad_h(a, __int_as_float(p23.y), g2);
            fmad_h(a, __int_as_float(p23.w), g3);
        }
        if (j + 2 <= end) {
            int4e p01 = *(const int4e*)(es + j);
            uint2 g0 = *((const uint2*)(xh + (size_t)p01.x * EMB) + q);
            uint2 g1 = *((const uint2*)(xh + (size_t)p01.z * EMB) + q);
            fmad_h(a, __int_as_float(p01.y), g0);
            fmad_h(a, __int_as_float(p01.w), g1);
            j += 2;
        }
        if (j < end) {
            int2 e0 = es[j];
            uint2 g0 = *((const uint2*)(xh + (size_t)e0.x * EMB) + q);
            fmad_h(a, __int_as_float(e0.y), g0);
        }
        size_t o = (size_t)r * 16 + q;
        if (mode < 2) {
            __half2 lo = __floats2half2_rn(a.x, a.y);
            __half2 hi = __floats2half2_rn(a.z, a.w);
            ((uint2*)yh)[o] = make_uint2(__builtin_bit_cast(unsigned, lo),
                                         __builtin_bit_cast(unsigned, hi));
        } else {
            uint2 u1 = ((const uint2*)y1h)[o];
            uint2 u2 = ((const uint2*)y2h)[o];
            float2 c1l = __half22float2(__builtin_bit_cast(__half2, u1.x));
            float2 c1h = __half22float2(__builtin_bit_cast(__half2, u1.y));
            float2 c2l = __half22float2(__builtin_bit_cast(__half2, u2.x));
            float2 c2h = __half22float2(__builtin_bit_cast(__half2, u2.y));
            const float4* b0 = (r < nu)
                ? ((const float4*)x0u + (size_t)r * 16)
                : ((const float4*)x0i + (size_t)(r - nu) * 16);
            float4 f0 = b0[q];
            f32x4 ac;
            ac.x = 0.25f * (f0.x + c1l.x + c2l.x + a.x);
            ac.y = 0.25f * (f0.y + c1l.y + c2l.y + a.y);
            ac.z = 0.25f * (f0.z + c1h.x + c2h.x + a.z);
            ac.w = 0.25f * (f0.w + c1h.y + c2h.y + a.w);
            __builtin_nontemporal_store(ac, (f32x4*)&out[o]);
        }
    }
}

// ---------------- single cooperative mega-kernel --------------------------
// P1 = {fp16 convert; coarse scatter} (independent, share one sync).
// 4 grid.syncs total. LDS 8 KB. No min-waves (round-5: forced spills).
__global__ __launch_bounds__(512) void mega(
        const int* __restrict__ rows, const int* __restrict__ cols,
        const float* __restrict__ vals,
        int* bcur, int2* __restrict__ es_raw, int2* __restrict__ es,
        int2* __restrict__ rbe,
        const float* __restrict__ ue, const float* __restrict__ ie,
        ushort_t* xh, ushort_t* y1h, ushort_t* y2h, float* out,
        int nu, int n_nodes, int n_edges, int nbkt) {
    cg::grid_group grid = cg::this_grid();
    __shared__ int lcnt[MAX_BKT];     // 2 KB (coarse)
    __shared__ int lbase[MAX_BKT];    // 2 KB (coarse)
    __shared__ int rcnt[BKT_ROWS];    // 2 KB (fine)
    __shared__ int rsc[BKT_ROWS];     // 2 KB (fine)
    int gid0 = blockIdx.x * blockDim.x + threadIdx.x;
    int gstride = gridDim.x * blockDim.x;

    // P1: fp16 convert + coarse scatter (bcur pre-zeroed by host memset)
    convert_body((const float4*)ue, (const float4*)ie, nu * 16,
                 (uint2*)xh, n_nodes * 16, gid0, gstride);
    coarse_body(rows, cols, vals, bcur, es_raw, n_edges, nbkt,
                lcnt, lbase, blockIdx.x, gridDim.x);
    grid.sync();

    // P2: fine permute es_raw -> es, emit rbe
    fine_body(bcur, es_raw, es, rbe, n_nodes, nbkt, rcnt, rsc,
              blockIdx.x, gridDim.x);
    grid.sync();

    // P3: layer 1, gather xh -> y1h
    spmm_body(rbe, es, xh, y1h, nullptr, nullptr, nullptr, nullptr, nu,
              nullptr, n_nodes, 0, gid0, gstride);
    grid.sync();

    // P4: layer 2, gather y1h -> y2h
    spmm_body(rbe, es, y1h, y2h, nullptr, nullptr, nullptr, nullptr, nu,
              nullptr, n_nodes, 1, gid0, gstride);
    grid.sync();

    // P5: layer 3, gather y2h; out = 0.25*(x0 + y1 + y2 + a)
    spmm_body(rbe, es, y2h, nullptr, y1h, y2h, ue, ie, nu,
              (float4*)out, n_nodes, 2, gid0, gstride);
}

// ---------------- fallback multi-dispatch kernels -------------------------

__global__ __launch_bounds__(512) void k_coarse(
        const int* __restrict__ rows, const int* __restrict__ cols,
        const float* __restrict__ vals, int* bcur, int2* __restrict__ es_raw,
        const float* __restrict__ ue, const float* __restrict__ ie,
        ushort_t* xh, int nu, int n_nodes, int n_edges, int nbkt) {
    __shared__ int lcnt[MAX_BKT];
    __shared__ int lbase[MAX_BKT];
    int gid0 = blockIdx.x * blockDim.x + threadIdx.x;
    int gstride = gridDim.x * blockDim.x;
    convert_body((const float4*)ue, (const float4*)ie, nu * 16,
                 (uint2*)xh, n_nodes * 16, gid0, gstride);
    coarse_body(rows, cols, vals, bcur, es_raw, n_edges, nbkt,
                lcnt, lbase, blockIdx.x, gridDim.x);
}

__global__ __launch_bounds__(512) void k_fine(
        const int* bcur, const int2* __restrict__ es_raw,
        int2* __restrict__ es, int2* __restrict__ rbe,
        int n_nodes, int nbkt) {
    __shared__ int rcnt[BKT_ROWS];
    __shared__ int rsc[BKT_ROWS];
    fine_body(bcur, es_raw, es, rbe, n_nodes, nbkt, rcnt, rsc,
              blockIdx.x, gridDim.x);
}

__global__ __launch_bounds__(256) void k_spmm(
        const int2* __restrict__ rbe, const int2* __restrict__ es,
        const ushort_t* xh, ushort_t* yh,
        const ushort_t* y1h, const ushort_t* y2h,
        const float* x0u, const float* x0i, int nu,
        float4* out, int n_nodes, int mode) {
    spmm_body(rbe, es, xh, yh, y1h, y2h, x0u, x0i, nu, out, n_nodes, mode,
              blockIdx.x * blockDim.x + threadIdx.x,
              gridDim.x * blockDim.x);
}

extern "C" void kernel_launch(void* const* d_in, const int* in_sizes, int n_in,
                              void* d_out, int out_size, void* d_ws, size_t ws_size,
                              hipStream_t stream) {
    const float* ue   = (const float*)d_in[0];
    const float* ie   = (const float*)d_in[1];
    const int*   rows = (const int*)d_in[2];
    const int*   cols = (const int*)d_in[3];
    const float* vals = (const float*)d_in[4];
    float* out = (float*)d_out;

    const int num_users = in_sizes[0] / EMB;
    const int num_items = in_sizes[1] / EMB;
    const int n_nodes   = num_users + num_items;
    const int n_edges   = in_sizes[2];
    const int nbkt      = (n_nodes + BKT_ROWS - 1) >> BKT_BITS;   // 293

    // Workspace (~80.4 MB):
    //  xh, y1h, y2h : fp16 embeddings (19.2 MB each)
    //  es, es_raw   : padded (col,val) lists (10.8 MB each)
    //  rbe (1.2 MB) | bcur (1.2 KB)
    const size_t buf_elems = (size_t)n_nodes * EMB;
    ushort_t* xh  = (ushort_t*)d_ws;
    ushort_t* y1h = xh + buf_elems;
    ushort_t* y2h = y1h + buf_elems;
    int2*  es     = (int2*)(y2h + buf_elems);
    int2*  es_raw = es + (size_t)nbkt * BKT_CAP;
    int2*  rbe    = es_raw + (size_t)nbkt * BKT_CAP;
    int*   bcur   = (int*)(rbe + n_nodes);

    int occ = 0, cus = 0, dev = 0;
    hipGetDevice(&dev);
    hipOccupancyMaxActiveBlocksPerMultiprocessor(&occ, mega, 512, 0);
    hipDeviceGetAttribute(&cus, hipDeviceAttributeMultiprocessorCount, dev);
    if (cus < 1) cus = 256;
    if (occ > 4) occ = 4;

    // zero bucket cursors (stream-ordered, before either path)
    hipMemsetAsync(bcur, 0, (size_t)nbkt * sizeof(int), stream);

    bool done = false;
    if (occ >= 3) {
        int grid_blocks = occ * cus;
        int nu = num_users, nn = n_nodes, ne = n_edges, nb = nbkt;
        void* args[] = { (void*)&rows, (void*)&cols, (void*)&vals,
                         (void*)&bcur, (void*)&es_raw, (void*)&es,
                         (void*)&rbe, (void*)&ue, (void*)&ie,
                         (void*)&xh, (void*)&y1h, (void*)&y2h, (void*)&out,
                         (void*)&nu, (void*)&nn, (void*)&ne, (void*)&nb };
        hipError_t err = hipLaunchCooperativeKernel(
            mega, dim3(grid_blocks), dim3(512), args, 0, stream);
        done = (err == hipSuccess);
        if (!done) (void)hipGetLastError();
    }

    if (!done) {
        // Fallback: identical device code, classic dispatches.
        int nchunk = (n_edges + CO_EDGES - 1) / CO_EDGES;
        k_coarse<<<nchunk, 512, 0, stream>>>(rows, cols, vals, bcur, es_raw,
                                             ue, ie, xh, num_users,
                                             n_nodes, n_edges, nbkt);
        k_fine<<<nbkt, 512, 0, stream>>>(bcur, es_raw, es, rbe,
                                         n_nodes, nbkt);
        int blocks = (n_nodes * 16 + 255) / 256;
        k_spmm<<<blocks, 256, 0, stream>>>(
            rbe, es, xh, y1h, nullptr, nullptr, nullptr, nullptr,
            num_users, nullptr, n_nodes, 0);
        k_spmm<<<blocks, 256, 0, stream>>>(
            rbe, es, y1h, y2h, nullptr, nullptr, nullptr, nullptr,
            num_users, nullptr, n_nodes, 1);
        k_spmm<<<blocks, 256, 0, stream>>>(
            rbe, es, y2h, nullptr, y1h, y2h, ue, ie,
            num_users, (float4*)out, n_nodes, 2);
    }
}

// Round 10
// 235.597 us; speedup vs baseline: 1.2185x; 1.0187x over previous
//
#include <hip/hip_runtime.h>
#include <hip/hip_fp16.h>
#include <hip/hip_cooperative_groups.h>

namespace cg = cooperative_groups;

#define EMB 64
#define BKT_BITS 9                 // 512 rows per bucket
#define BKT_ROWS (1 << BKT_BITS)
#define BKT_CAP 4608               // fixed bucket capacity (mean 4096, +8 sigma)
#define MAX_BKT 512                // supports up to 262144 nodes
#define CO_EDGES 2048              // edges per coarse chunk (~586 chunks)

typedef float f32x4 __attribute__((ext_vector_type(4)));
typedef int int4e __attribute__((ext_vector_type(4), aligned(8)));
typedef unsigned short ushort_t;

// ---------------- shared device bodies (used by mega + fallback) ----------

// Convert fp32 [ue;ie] -> contiguous fp16 xh (the gathered operand).
__device__ void convert_body(const float4* __restrict__ ue4,
                             const float4* __restrict__ ie4,
                             int nu16, uint2* __restrict__ xh2,
                             int lanes, int gid0, int gstride) {
    for (int o = gid0; o < lanes; o += gstride) {
        float4 v = (o < nu16) ? ue4[o] : ie4[o - nu16];
        __half2 lo = __floats2half2_rn(v.x, v.y);
        __half2 hi = __floats2half2_rn(v.z, v.w);
        xh2[o] = make_uint2(__builtin_bit_cast(unsigned, lo),
                            __builtin_bit_cast(unsigned, hi));
    }
}

// Coarse scatter: bin a chunk by bucket in LDS, reserve per-bucket ranges
// with one global atomic per (chunk,bucket), scatter into fixed regions of
// es_raw. Packs row's low 9 bits above the 18-bit col.
__device__ void coarse_body(const int* __restrict__ rows,
                            const int* __restrict__ cols,
                            const float* __restrict__ vals,
                            int* bcur, int2* __restrict__ es_raw,
                            int n_edges, int nbkt,
                            int* lcnt, int* lbase,
                            int cstart, int cstride) {
    int tid = threadIdx.x;           // blockDim.x == 512
    int nchunk = (n_edges + CO_EDGES - 1) / CO_EDGES;
    for (int c = cstart; c < nchunk; c += cstride) {
        for (int i = tid; i < nbkt; i += 512) lcnt[i] = 0;
        __syncthreads();
        int e0 = c * CO_EDGES;
        int e1 = min(e0 + CO_EDGES, n_edges);
        for (int e = e0 + tid; e < e1; e += 512)
            atomicAdd(&lcnt[rows[e] >> BKT_BITS], 1);
        __syncthreads();
        for (int i = tid; i < nbkt; i += 512) {
            int cc = lcnt[i];
            lbase[i] = cc ? atomicAdd(&bcur[i], cc) : 0;
        }
        __syncthreads();
        for (int e = e0 + tid; e < e1; e += 512) {
            int r = rows[e];
            int b = r >> BKT_BITS;
            int p = atomicAdd(&lbase[b], 1);
            if (p < BKT_CAP)   // statistically unreachable; guards corruption
                es_raw[(size_t)b * BKT_CAP + p] =
                    make_int2(cols[e] | ((r & (BKT_ROWS - 1)) << 18),
                              __float_as_int(vals[e]));
        }
        __syncthreads();
    }
}

// Fine permute (plain row grouping). Two passes over es_raw (L2-resident):
// count -> LDS scan (emits per-row [beg,end) coalesced) -> permute into
// row-grouped es. LDS 4 KB.
__device__ void fine_body(const int* bcur,
                          const int2* __restrict__ es_raw,
                          int2* __restrict__ es,
                          int2* __restrict__ rbe, int n_nodes, int nbkt,
                          int* rcnt, int* rsc,
                          int bstart, int bstride) {
    int tid = threadIdx.x;          // blockDim.x == 512 == BKT_ROWS
    for (int b = bstart; b < nbkt; b += bstride) {
        int cnt = min(bcur[b], BKT_CAP);
        int base = b * BKT_CAP;
        rcnt[tid] = 0;
        __syncthreads();
        for (int j = tid; j < cnt; j += BKT_ROWS)
            atomicAdd(&rcnt[es_raw[base + j].x >> 18], 1);
        __syncthreads();
        int v = rcnt[tid];
        rsc[tid] = v;
        __syncthreads();
        for (int d = 1; d < BKT_ROWS; d <<= 1) {
            int t = (tid >= d) ? rsc[tid - d] : 0;
            __syncthreads();
            rsc[tid] += t;
            __syncthreads();
        }
        int excl = rsc[tid] - v;
        rcnt[tid] = excl;           // fill cursor
        int r = (b << BKT_BITS) + tid;
        if (r < n_nodes) rbe[r] = make_int2(base + excl, base + excl + v);
        __syncthreads();
        for (int j = tid; j < cnt; j += BKT_ROWS) {
            int2 e = es_raw[base + j];
            int p = atomicAdd(&rcnt[e.x >> 18], 1);
            es[base + p] = make_int2(e.x & 0x3FFFF, e.y);
        }
        __syncthreads();
    }
}

// 16-B fp16 fragment (8 halves) -> fp32 FMA into two float4 accumulators.
__device__ __forceinline__ void fmad8(f32x4& a0, f32x4& a1, float v, uint4 g) {
    float2 f0 = __half22float2(__builtin_bit_cast(__half2, g.x));
    float2 f1 = __half22float2(__builtin_bit_cast(__half2, g.y));
    float2 f2 = __half22float2(__builtin_bit_cast(__half2, g.z));
    float2 f3 = __half22float2(__builtin_bit_cast(__half2, g.w));
    a0.x += v * f0.x; a0.y += v * f0.y; a0.z += v * f1.x; a0.w += v * f1.y;
    a1.x += v * f2.x; a1.y += v * f2.y; a1.z += v * f3.x; a1.w += v * f3.y;
}

// Row-parallel SpMM, 8 lanes/row x 16-B gathers (round-10 change: halves
// the VMEM request count per edge vs 16x8B -- bytes were halved in round 9
// but time only fell 16%, so the pipe is request-bound, not byte-bound).
// 4-wide edge unroll, fp32 accumulation (2x float4 per lane).
// mode 0/1: yh[o] = fp16(a), plain 16-B store.
// mode 2:   out = 0.25*(x0_fp32 + y1h + y2h + a), two NT fp32 stores.
__device__ void spmm_body(const int2* __restrict__ rbe,
                          const int2* __restrict__ es,
                          const ushort_t* __restrict__ xh,
                          ushort_t* __restrict__ yh,
                          const ushort_t* __restrict__ y1h,
                          const ushort_t* __restrict__ y2h,
                          const float* __restrict__ x0u,
                          const float* __restrict__ x0i, int nu,
                          float4* __restrict__ out,
                          int n_nodes, int mode, int gid0, int gstride) {
    int lanes = n_nodes * 8;
    for (int gid = gid0; gid < lanes; gid += gstride) {
        int r = gid >> 3;
        int q = gid & 7;
        int2 be = rbe[r];
        int j = be.x;
        int end = be.y;
        f32x4 a0 = {0.f, 0.f, 0.f, 0.f};
        f32x4 a1 = {0.f, 0.f, 0.f, 0.f};
        for (; j + 4 <= end; j += 4) {
            int4e p01 = *(const int4e*)(es + j);       // edges j, j+1
            int4e p23 = *(const int4e*)(es + j + 2);   // edges j+2, j+3
            uint4 g0 = *((const uint4*)(xh + (size_t)p01.x * EMB) + q);
            uint4 g1 = *((const uint4*)(xh + (size_t)p01.z * EMB) + q);
            uint4 g2 = *((const uint4*)(xh + (size_t)p23.x * EMB) + q);
            uint4 g3 = *((const uint4*)(xh + (size_t)p23.z * EMB) + q);
            fmad8(a0, a1, __int_as_float(p01.y), g0);
            fmad8(a0, a1, __int_as_float(p01.w), g1);
            fmad8(a0, a1, __int_as_float(p23.y), g2);
            fmad8(a0, a1, __int_as_float(p23.w), g3);
        }
        if (j + 2 <= end) {
            int4e p01 = *(const int4e*)(es + j);
            uint4 g0 = *((const uint4*)(xh + (size_t)p01.x * EMB) + q);
            uint4 g1 = *((const uint4*)(xh + (size_t)p01.z * EMB) + q);
            fmad8(a0, a1, __int_as_float(p01.y), g0);
            fmad8(a0, a1, __int_as_float(p01.w), g1);
            j += 2;
        }
        if (j < end) {
            int2 e0 = es[j];
            uint4 g0 = *((const uint4*)(xh + (size_t)e0.x * EMB) + q);
            fmad8(a0, a1, __int_as_float(e0.y), g0);
        }
        size_t o = (size_t)r * 8 + q;
        if (mode < 2) {
            uint4 pk;
            pk.x = __builtin_bit_cast(unsigned, __floats2half2_rn(a0.x, a0.y));
            pk.y = __builtin_bit_cast(unsigned, __floats2half2_rn(a0.z, a0.w));
            pk.z = __builtin_bit_cast(unsigned, __floats2half2_rn(a1.x, a1.y));
            pk.w = __builtin_bit_cast(unsigned, __floats2half2_rn(a1.z, a1.w));
            ((uint4*)yh)[o] = pk;
        } else {
            uint4 u1 = ((const uint4*)y1h)[o];
            uint4 u2 = ((const uint4*)y2h)[o];
            float2 c10 = __half22float2(__builtin_bit_cast(__half2, u1.x));
            float2 c11 = __half22float2(__builtin_bit_cast(__half2, u1.y));
            float2 c12 = __half22float2(__builtin_bit_cast(__half2, u1.z));
            float2 c13 = __half22float2(__builtin_bit_cast(__half2, u1.w));
            float2 c20 = __half22float2(__builtin_bit_cast(__half2, u2.x));
            float2 c21 = __half22float2(__builtin_bit_cast(__half2, u2.y));
            float2 c22 = __half22float2(__builtin_bit_cast(__half2, u2.z));
            float2 c23 = __half22float2(__builtin_bit_cast(__half2, u2.w));
            const float4* b0 = (r < nu)
                ? ((const float4*)x0u + (size_t)r * 16)
                : ((const float4*)x0i + (size_t)(r - nu) * 16);
            float4 f0a = b0[2 * q];
            float4 f0b = b0[2 * q + 1];
            f32x4 oa, ob;
            oa.x = 0.25f * (f0a.x + c10.x + c20.x + a0.x);
            oa.y = 0.25f * (f0a.y + c10.y + c20.y + a0.y);
            oa.z = 0.25f * (f0a.z + c11.x + c21.x + a0.z);
            oa.w = 0.25f * (f0a.w + c11.y + c21.y + a0.w);
            ob.x = 0.25f * (f0b.x + c12.x + c22.x + a1.x);
            ob.y = 0.25f * (f0b.y + c12.y + c22.y + a1.y);
            ob.z = 0.25f * (f0b.z + c13.x + c23.x + a1.z);
            ob.w = 0.25f * (f0b.w + c13.y + c23.y + a1.w);
            size_t oo = (size_t)r * 16 + 2 * q;
            __builtin_nontemporal_store(oa, (f32x4*)&out[oo]);
            __builtin_nontemporal_store(ob, (f32x4*)&out[oo + 1]);
        }
    }
}

// ---------------- single cooperative mega-kernel --------------------------
// P1 = {fp16 convert; coarse scatter}; 4 grid.syncs total. LDS 8 KB.
// No min-waves in launch_bounds (round-5: (512,6) forced spills).
__global__ __launch_bounds__(512) void mega(
        const int* __restrict__ rows, const int* __restrict__ cols,
        const float* __restrict__ vals,
        int* bcur, int2* __restrict__ es_raw, int2* __restrict__ es,
        int2* __restrict__ rbe,
        const float* __restrict__ ue, const float* __restrict__ ie,
        ushort_t* xh, ushort_t* y1h, ushort_t* y2h, float* out,
        int nu, int n_nodes, int n_edges, int nbkt) {
    cg::grid_group grid = cg::this_grid();
    __shared__ int lcnt[MAX_BKT];     // 2 KB (coarse)
    __shared__ int lbase[MAX_BKT];    // 2 KB (coarse)
    __shared__ int rcnt[BKT_ROWS];    // 2 KB (fine)
    __shared__ int rsc[BKT_ROWS];     // 2 KB (fine)
    int gid0 = blockIdx.x * blockDim.x + threadIdx.x;
    int gstride = gridDim.x * blockDim.x;

    // P1: fp16 convert + coarse scatter (bcur pre-zeroed by host memset)
    convert_body((const float4*)ue, (const float4*)ie, nu * 16,
                 (uint2*)xh, n_nodes * 16, gid0, gstride);
    coarse_body(rows, cols, vals, bcur, es_raw, n_edges, nbkt,
                lcnt, lbase, blockIdx.x, gridDim.x);
    grid.sync();

    // P2: fine permute es_raw -> es, emit rbe
    fine_body(bcur, es_raw, es, rbe, n_nodes, nbkt, rcnt, rsc,
              blockIdx.x, gridDim.x);
    grid.sync();

    // P3: layer 1, gather xh -> y1h
    spmm_body(rbe, es, xh, y1h, nullptr, nullptr, nullptr, nullptr, nu,
              nullptr, n_nodes, 0, gid0, gstride);
    grid.sync();

    // P4: layer 2, gather y1h -> y2h
    spmm_body(rbe, es, y1h, y2h, nullptr, nullptr, nullptr, nullptr, nu,
              nullptr, n_nodes, 1, gid0, gstride);
    grid.sync();

    // P5: layer 3, gather y2h; out = 0.25*(x0 + y1 + y2 + a)
    spmm_body(rbe, es, y2h, nullptr, y1h, y2h, ue, ie, nu,
              (float4*)out, n_nodes, 2, gid0, gstride);
}

// ---------------- fallback multi-dispatch kernels -------------------------

__global__ __launch_bounds__(512) void k_coarse(
        const int* __restrict__ rows, const int* __restrict__ cols,
        const float* __restrict__ vals, int* bcur, int2* __restrict__ es_raw,
        const float* __restrict__ ue, const float* __restrict__ ie,
        ushort_t* xh, int nu, int n_nodes, int n_edges, int nbkt) {
    __shared__ int lcnt[MAX_BKT];
    __shared__ int lbase[MAX_BKT];
    int gid0 = blockIdx.x * blockDim.x + threadIdx.x;
    int gstride = gridDim.x * blockDim.x;
    convert_body((const float4*)ue, (const float4*)ie, nu * 16,
                 (uint2*)xh, n_nodes * 16, gid0, gstride);
    coarse_body(rows, cols, vals, bcur, es_raw, n_edges, nbkt,
                lcnt, lbase, blockIdx.x, gridDim.x);
}

__global__ __launch_bounds__(512) void k_fine(
        const int* bcur, const int2* __restrict__ es_raw,
        int2* __restrict__ es, int2* __restrict__ rbe,
        int n_nodes, int nbkt) {
    __shared__ int rcnt[BKT_ROWS];
    __shared__ int rsc[BKT_ROWS];
    fine_body(bcur, es_raw, es, rbe, n_nodes, nbkt, rcnt, rsc,
              blockIdx.x, gridDim.x);
}

__global__ __launch_bounds__(256) void k_spmm(
        const int2* __restrict__ rbe, const int2* __restrict__ es,
        const ushort_t* xh, ushort_t* yh,
        const ushort_t* y1h, const ushort_t* y2h,
        const float* x0u, const float* x0i, int nu,
        float4* out, int n_nodes, int mode) {
    spmm_body(rbe, es, xh, yh, y1h, y2h, x0u, x0i, nu, out, n_nodes, mode,
              blockIdx.x * blockDim.x + threadIdx.x,
              gridDim.x * blockDim.x);
}

extern "C" void kernel_launch(void* const* d_in, const int* in_sizes, int n_in,
                              void* d_out, int out_size, void* d_ws, size_t ws_size,
                              hipStream_t stream) {
    const float* ue   = (const float*)d_in[0];
    const float* ie   = (const float*)d_in[1];
    const int*   rows = (const int*)d_in[2];
    const int*   cols = (const int*)d_in[3];
    const float* vals = (const float*)d_in[4];
    float* out = (float*)d_out;

    const int num_users = in_sizes[0] / EMB;
    const int num_items = in_sizes[1] / EMB;
    const int n_nodes   = num_users + num_items;
    const int n_edges   = in_sizes[2];
    const int nbkt      = (n_nodes + BKT_ROWS - 1) >> BKT_BITS;   // 293

    // Workspace (~80.4 MB):
    //  xh, y1h, y2h : fp16 embeddings (19.2 MB each)
    //  es, es_raw   : padded (col,val) lists (10.8 MB each)
    //  rbe (1.2 MB) | bcur (1.2 KB)
    const size_t buf_elems = (size_t)n_nodes * EMB;
    ushort_t* xh  = (ushort_t*)d_ws;
    ushort_t* y1h = xh + buf_elems;
    ushort_t* y2h = y1h + buf_elems;
    int2*  es     = (int2*)(y2h + buf_elems);
    int2*  es_raw = es + (size_t)nbkt * BKT_CAP;
    int2*  rbe    = es_raw + (size_t)nbkt * BKT_CAP;
    int*   bcur   = (int*)(rbe + n_nodes);

    int occ = 0, cus = 0, dev = 0;
    hipGetDevice(&dev);
    hipOccupancyMaxActiveBlocksPerMultiprocessor(&occ, mega, 512, 0);
    hipDeviceGetAttribute(&cus, hipDeviceAttributeMultiprocessorCount, dev);
    if (cus < 1) cus = 256;
    if (occ > 4) occ = 4;

    // zero bucket cursors (stream-ordered, before either path)
    hipMemsetAsync(bcur, 0, (size_t)nbkt * sizeof(int), stream);

    bool done = false;
    if (occ >= 3) {
        int grid_blocks = occ * cus;
        int nu = num_users, nn = n_nodes, ne = n_edges, nb = nbkt;
        void* args[] = { (void*)&rows, (void*)&cols, (void*)&vals,
                         (void*)&bcur, (void*)&es_raw, (void*)&es,
                         (void*)&rbe, (void*)&ue, (void*)&ie,
                         (void*)&xh, (void*)&y1h, (void*)&y2h, (void*)&out,
                         (void*)&nu, (void*)&nn, (void*)&ne, (void*)&nb };
        hipError_t err = hipLaunchCooperativeKernel(
            mega, dim3(grid_blocks), dim3(512), args, 0, stream);
        done = (err == hipSuccess);
        if (!done) (void)hipGetLastError();
    }

    if (!done) {
        // Fallback: identical device code, classic dispatches.
        int nchunk = (n_edges + CO_EDGES - 1) / CO_EDGES;
        k_coarse<<<nchunk, 512, 0, stream>>>(rows, cols, vals, bcur, es_raw,
                                             ue, ie, xh, num_users,
                                             n_nodes, n_edges, nbkt);
        k_fine<<<nbkt, 512, 0, stream>>>(bcur, es_raw, es, rbe,
                                         n_nodes, nbkt);
        int blocks = (n_nodes * 8 + 255) / 256;
        k_spmm<<<blocks, 256, 0, stream>>>(
            rbe, es, xh, y1h, nullptr, nullptr, nullptr, nullptr,
            num_users, nullptr, n_nodes, 0);
        k_spmm<<<blocks, 256, 0, stream>>>(
            rbe, es, y1h, y2h, nullptr, nullptr, nullptr, nullptr,
            num_users, nullptr, n_nodes, 1);
        k_spmm<<<blocks, 256, 0, stream>>>(
            rbe, es, y2h, nullptr, y1h, y2h, ue, ie,
            num_users, (float4*)out, n_nodes, 2);
    }
}